// Round 4
// baseline (2312.262 us; speedup 1.0000x reference)
//
#include <hip/hip_runtime.h>
#include <cmath>

#ifndef M_PI
#define M_PI 3.14159265358979323846
#endif

#define T_LEN   160000
#define NSEG    155
#define ROWS    32
#define NBANDS  8

#define CHUNK   256                  // samples per barrier interval
#define NSUB    4                    // sub-chunks of 64
#define NQ      16                   // float4 quads per sub-chunk
#define QPC     64                   // quads per chunk
#define NCHUNK  624                  // 256*624 = 159744 = all samples any segment uses
#define TOT_IT  (NCHUNK + 2)         // 3-stage pipeline drain
#define LOUD_FLOATS (NBANDS * 2 * ROWS * NSEG)   // 79360

struct AllCoefs {
    float h[NBANDS][5];   // b0 b1 b2 a1 a2 (a0-normalized, f32-cast like np.float32)
    float l[NBANDS][5];
};

// Workgroup barrier without the vmcnt(0) drain (only LDS carries inter-wave
// data; w0's global prefetch stays in flight across the barrier).
__device__ __forceinline__ void barrier_lds_only() {
    asm volatile("s_waitcnt lgkmcnt(0)\n\ts_barrier" ::: "memory");
}

// ============================ Fused pipeline =============================
// One block per (band, src): 32 chains, 3 waves, 256 samples per barrier.
//   w0 : hp biquad   global x (sub-chunk ping-pong prefetch) -> I1
//   w1 : lp biquad   I1 -> I2
//   w2 : weighting, dual parity: lanes 0-31 even segments, 32-63 odd
// R4 change (serial-schedule theory): R0-R3 all measured ~31 cyc/sample,
// matching FULLY-SERIAL execution of each sample's 5-op chain (5 x 4-cyc
// latency = 20 + LDS). Only the 2 feedback FMAs are truly serial; the FIR
// half depends on inputs only. Each stage is now TWO loops per sub-chunk:
//   loop1: f[i] = FIR(x)    -- independent across samples, full ILP
//   loop2: y    = REC(f[i]) -- pure 8-cyc/sample dependence chain
// Per-op inputs and per-op order are IDENTICAL to the kernel verified
// BIT-EXACT vs the np reference (absmax 0.0) — only cross-sample
// scheduling freedom is exposed.
__global__ __launch_bounds__(192, 1)
void tf_pipe3_kernel(const float* __restrict__ sig, const float* __restrict__ wm,
                     float* __restrict__ loud, AllCoefs C) {
    __shared__ float I1[2][CHUNK * 32];   // hp -> lp       (64 KiB)
    __shared__ float I2[2][CHUNK * 32];   // lp -> weight   (64 KiB)

    const int band = blockIdx.x;
    const int src  = blockIdx.y;              // 0 = signal, 1 = watermark
    const int tid  = threadIdx.x;
    const int wid  = tid >> 6;
    const int lane = tid & 63;
    const int ch   = lane & 31;               // chain = batch row

    const float hb0 = C.h[band][0], hb1 = C.h[band][1], hb2 = C.h[band][2];
    const float hna1 = -C.h[band][3], hna2 = -C.h[band][4];
    const float lb0 = C.l[band][0], lb1 = C.l[band][1], lb2 = C.l[band][2];
    const float lna1 = -C.l[band][3], lna2 = -C.l[band][4];
    const float NA1 =  1.79999995231628417969f; // -np.float32(-1.8)
    const float NA2 = -0.810000002384185791f;   // -np.float32(0.81)

    const float* __restrict__ xrow = (src ? wm : sig) + (size_t)ch * T_LEN;
    const float4* __restrict__ xq  = (const float4*)xrow;   // global quad array

    float x1 = 0.f, x2 = 0.f, y1 = 0.f, y2 = 0.f, acc = 0.f;

    float4 pfA[NQ], pfB[NQ];                  // sub-chunk ping-pong prefetch
    if (wid == 0 && lane < 32) {
        #pragma unroll
        for (int i = 0; i < NQ; ++i) pfA[i] = xq[i];   // chunk 0, sub 0
    }

// ---- hp split: FIR (input-only deps, full ILP) / REC (feedback chain) ----
#define HPF(xx, ff) { float s1_ = __fmaf_rn(hb0, xx, __fmul_rn(hb1, x1)); \
                      ff = __fmaf_rn(hb2, x2, s1_); x2 = x1; x1 = xx; }
#define HPR(ff, oo) { float s3_ = __fmaf_rn(hna1, y1, ff); \
                      oo = __fmaf_rn(hna2, y2, s3_); y2 = y1; y1 = oo; }
// ---- lp split ----
#define LPF(xx, ff) { float s1_ = __fmaf_rn(lb0, xx, __fmul_rn(lb1, x1)); \
                      ff = __fmaf_rn(lb2, x2, s1_); x2 = x1; x1 = xx; }
#define LPR(ff, oo) { float s3_ = __fmaf_rn(lna1, y1, ff); \
                      oo = __fmaf_rn(lna2, y2, s3_); y2 = y1; y1 = oo; }
// ---- weighting split (s1 = fma(-2,x1,x): product exact, bit-identical) ----
#define WF(xx, ff)  { float s1_ = __fmaf_rn(-2.0f, x1, xx); \
                      ff = __fadd_rn(s1_, x2); x2 = x1; x1 = xx; }
#define WR(ff)      { float s3_ = __fmaf_rn(NA1, y1, ff); \
                      float yy_ = __fmaf_rn(NA2, y2, s3_); \
                      y2 = y1; y1 = yy_; acc = __fmaf_rn(yy_, yy_, acc); }

// w0 sub-chunk: consume USE (holds sub `s` of chunk `cc`), refill FILL from
// quad base NEXTQ (next sub-chunk; for s=3 that's chunk cc+1 sub 0 — loads
// stay in flight across the lds-only barrier). FIR loop first (ILP + load
// issue), then the pure REC chain + LDS stores.
#define W0SUB(USE, FILL, cc, s, NEXTQ)                                       \
    {                                                                        \
        float4* __restrict__ ob = (float4*)I1[(cc) & 1];                     \
        float4 f[NQ];                                                        \
        _Pragma("unroll")                                                    \
        for (int i = 0; i < NQ; ++i) {                                       \
            float4 v = USE[i];                                               \
            FILL[i] = xq[(NEXTQ) + i];                                       \
            HPF(v.x, f[i].x) HPF(v.y, f[i].y) HPF(v.z, f[i].z) HPF(v.w, f[i].w) \
        }                                                                    \
        _Pragma("unroll")                                                    \
        for (int i = 0; i < NQ; ++i) {                                       \
            float4 o;                                                        \
            HPR(f[i].x, o.x) HPR(f[i].y, o.y) HPR(f[i].z, o.z) HPR(f[i].w, o.w) \
            ob[((s) * NQ + i) * 32 + ch] = o;                                \
        }                                                                    \
    }

    for (int iter = 0; iter < TOT_IT; ++iter) {
        if (wid == 0) {
            if (iter < NCHUNK && lane < 32) {
                const int c = iter;
                const int q0 = c * QPC;
                // invariant: pfA holds sub 0 of chunk c
                W0SUB(pfA, pfB, c, 0, q0 + 1 * NQ)
                W0SUB(pfB, pfA, c, 1, q0 + 2 * NQ)
                W0SUB(pfA, pfB, c, 2, q0 + 3 * NQ)
                W0SUB(pfB, pfA, c, 3, q0 + 4 * NQ)   // next chunk sub 0
                // max prefetch: c=623 -> quads 39936..39951 -> sample 159807 < 160000
            }
        } else if (wid == 1) {
            if (iter >= 1 && iter <= NCHUNK && lane < 32) {
                const int c = iter - 1;
                const float4* __restrict__ ib = (const float4*)I1[c & 1];
                float4* __restrict__ ob = (float4*)I2[c & 1];
                #pragma unroll
                for (int s = 0; s < NSUB; ++s) {
                    float4 v[NQ];
                    #pragma unroll
                    for (int i = 0; i < NQ; ++i) v[i] = ib[(s * NQ + i) * 32 + ch];
                    float4 f[NQ];
                    #pragma unroll
                    for (int i = 0; i < NQ; ++i) {
                        LPF(v[i].x, f[i].x) LPF(v[i].y, f[i].y)
                        LPF(v[i].z, f[i].z) LPF(v[i].w, f[i].w)
                    }
                    #pragma unroll
                    for (int i = 0; i < NQ; ++i) {
                        float4 o;
                        LPR(f[i].x, o.x) LPR(f[i].y, o.y)
                        LPR(f[i].z, o.z) LPR(f[i].w, o.w)
                        ob[(s * NQ + i) * 32 + ch] = o;
                    }
                }
            }
        } else {
            if (iter >= 2) {
                const int c = iter - 2;
                const bool evenHalf = (lane < 32);
                const float4* __restrict__ ib = (const float4*)I2[c & 1];
                #pragma unroll
                for (int s = 0; s < NSUB; ++s) {
                    const int u = c * NSUB + s;       // global 64-sample index
                    const int m32 = u & 31;
                    // segment j = u/16 starts at sub-chunk u when u%32==0 (even j) or 16 (odd j)
                    const bool rst = (m32 == (evenHalf ? 0 : 16)) && ((u >> 4) < NSEG);
                    if (rst) { x1 = 0.f; x2 = 0.f; }          // FIR state reset
                    float4 v[NQ];
                    #pragma unroll
                    for (int i = 0; i < NQ; ++i) v[i] = ib[(s * NQ + i) * 32 + ch];
                    float4 f[NQ];
                    #pragma unroll
                    for (int i = 0; i < NQ; ++i) {
                        WF(v[i].x, f[i].x) WF(v[i].y, f[i].y)
                        WF(v[i].z, f[i].z) WF(v[i].w, f[i].w)
                    }
                    if (rst) { y1 = 0.f; y2 = 0.f; acc = 0.f; }   // REC state reset
                    #pragma unroll
                    for (int i = 0; i < NQ; ++i) {
                        WR(f[i].x) WR(f[i].y) WR(f[i].z) WR(f[i].w)
                    }
                    // even seg ends when u%32==31; odd when u%32==15 (u>=31); j=(u-31)/16
                    const int endm = evenHalf ? 31 : 15;
                    if (m32 == endm && u >= 31) {
                        const int j = (u - 31) >> 4;
                        float e = __fmul_rn(acc, 0.00048828125f);   // /2048 exact
                        loud[((size_t)((band * 2 + src) * ROWS + ch)) * NSEG + j] =
                            __fmul_rn(10.0f, log10f(__fadd_rn(e, 1e-8f)));
                    }
                }
            }
        }
        barrier_lds_only();
    }
#undef W0SUB
#undef HPF
#undef HPR
#undef LPF
#undef LPR
#undef WF
#undef WR
}

__global__ __launch_bounds__(256)
void tf_reduce_kernel(const float* __restrict__ loud, float* __restrict__ out) {
    __shared__ double sh[256];
    const int per_band = ROWS * NSEG;       // 4960
    const int npairs   = NBANDS * per_band; // 39680
    double s = 0.0;
    for (int idx = threadIdx.x; idx < npairs; idx += 256) {
        int band = idx / per_band;
        int rs   = idx - band * per_band;
        float a = loud[(size_t)(band * 2 + 0) * per_band + rs];
        float b = loud[(size_t)(band * 2 + 1) * per_band + rs];
        s += fabs((double)b - (double)a);
    }
    sh[threadIdx.x] = s;
    __syncthreads();
    for (int off = 128; off > 0; off >>= 1) {
        if (threadIdx.x < off) sh[threadIdx.x] += sh[threadIdx.x + off];
        __syncthreads();
    }
    if (threadIdx.x == 0) out[0] = (float)(sh[0] / (double)npairs);
}

// Host-side coefficients: f64 with the reference's exact expression order,
// then cast each to f32 (mirrors tuple(np.float32(v / a0) ...)).
static void mk_hp(double cutoff, float* o) {
    const double w0    = 2.0 * M_PI * cutoff / 16000.0;
    const double alpha = sin(w0) / (2.0 * 0.707);
    const double cw    = cos(w0);
    const double b0 = (1.0 + cw) / 2.0;
    const double b1 = -(1.0 + cw);
    const double b2 = (1.0 + cw) / 2.0;
    const double a0 = 1.0 + alpha;
    const double a1 = -2.0 * cw;
    const double a2 = 1.0 - alpha;
    o[0] = (float)(b0 / a0); o[1] = (float)(b1 / a0); o[2] = (float)(b2 / a0);
    o[3] = (float)(a1 / a0); o[4] = (float)(a2 / a0);
}

static void mk_lp(double cutoff, float* o) {
    const double w0    = 2.0 * M_PI * cutoff / 16000.0;
    const double alpha = sin(w0) / (2.0 * 0.707);
    const double cw    = cos(w0);
    const double b0 = (1.0 - cw) / 2.0;
    const double b1 = 1.0 - cw;
    const double b2 = (1.0 - cw) / 2.0;
    const double a0 = 1.0 + alpha;
    const double a1 = -2.0 * cw;
    const double a2 = 1.0 - alpha;
    o[0] = (float)(b0 / a0); o[1] = (float)(b1 / a0); o[2] = (float)(b2 / a0);
    o[3] = (float)(a1 / a0); o[4] = (float)(a2 / a0);
}

extern "C" void kernel_launch(void* const* d_in, const int* in_sizes, int n_in,
                              void* d_out, int out_size, void* d_ws, size_t ws_size,
                              hipStream_t stream) {
    const float* sig = (const float*)d_in[0];
    const float* wm  = (const float*)d_in[1];
    float* loud = (float*)d_ws;   // 79360 floats = 310 KiB

    AllCoefs C;
    for (int i = 0; i < NBANDS; ++i) {
        mk_hp(1000.0 * (double)i,       C.h[i]);   // low_cut  = i*1000 exactly
        mk_lp(1000.0 * (double)(i + 1), C.l[i]);   // high_cut = (i+1)*1000 exactly
    }

    tf_pipe3_kernel<<<dim3(NBANDS, 2), 192, 0, stream>>>(sig, wm, loud, C);
    tf_reduce_kernel<<<1, 256, 0, stream>>>(loud, (float*)d_out);
}

// Round 5
// 2203.616 us; speedup vs baseline: 1.0493x; 1.0493x over previous
//
#include <hip/hip_runtime.h>
#include <cmath>

#ifndef M_PI
#define M_PI 3.14159265358979323846
#endif

#define T_LEN   160000
#define NSEG    155
#define ROWS    32
#define NBANDS  8

#define CHUNK   192                  // samples per barrier interval
#define NSUB    3                    // sub-chunks of 64
#define NQ      16                   // float4 quads per sub-chunk per chain
#define QPC     48                   // quads per chunk per chain
#define NCHUNK  832                  // 192*832 = 159744 = all samples any segment uses
#define TOT_IT  (NCHUNK + 2)         // 3-stage pipeline drain
#define LOUD_FLOATS (NBANDS * 2 * ROWS * NSEG)   // 79360

struct AllCoefs {
    float h[NBANDS][5];   // b0 b1 b2 a1 a2 (a0-normalized, f32-cast like np.float32)
    float l[NBANDS][5];
};

// Workgroup barrier without the vmcnt(0) drain (only LDS carries inter-wave
// data; w0's global prefetch stays in flight across the barrier).
__device__ __forceinline__ void barrier_lds_only() {
    asm volatile("s_waitcnt lgkmcnt(0)\n\ts_barrier" ::: "memory");
}

// ============================ Fused pipeline =============================
// R5 = R3 pipe4 (verified bit-exact, steady 2089 us) + latency-stall fixes.
// One block per BAND (8 blocks), 64 lanes = 2 srcs x 32 rows, 4 waves:
//   w0 : hp biquad   global x -> slot c%3        [prefetch distance 2 subs]
//   w1 : lp biquad   IN-PLACE transform slot (c-1)%3   [LDS read-ahead 1 sub]
//   w2 : weighting even-parity segments          [LDS read-ahead 1 sub]
//   w3 : weighting odd-parity segments           [LDS read-ahead 1 sub]
// 3-slot rotating LDS buffer (3 x 48 KiB).  Stall theory: w0's old
// distance-1 prefetch (~450 cyc cover at 4-cyc/instr single-wave cadence)
// < HBM latency (~700-900); consumers exposed ~120-cyc LDS latency per
// sub-chunk.  Distance-2 global prefetch + explicit vA/vB LDS read-ahead
// hide both.  Per-chain arithmetic ops and their ORDER are bit-identical
// to the BIT-EXACT verified kernel (absmax 0.0).
__global__ __launch_bounds__(256, 1)
void tf_pipe4_kernel(const float* __restrict__ sig, const float* __restrict__ wm,
                     float* __restrict__ loud, AllCoefs C) {
    __shared__ float4 I[3][QPC * 64];          // 3 x 48 KiB = 144 KiB

    const int band = blockIdx.x;
    const int tid  = threadIdx.x;
    const int wid  = tid >> 6;                 // 0..3
    const int lane = tid & 63;
    const int row  = lane & 31;                // batch row
    const int src  = lane >> 5;                // 0 = signal, 1 = watermark

    const float hb0 = C.h[band][0], hb1 = C.h[band][1], hb2 = C.h[band][2];
    const float hna1 = -C.h[band][3], hna2 = -C.h[band][4];
    const float lb0 = C.l[band][0], lb1 = C.l[band][1], lb2 = C.l[band][2];
    const float lna1 = -C.l[band][3], lna2 = -C.l[band][4];
    const float NA1 =  1.79999995231628417969f; // -np.float32(-1.8)
    const float NA2 = -0.810000002384185791f;   // -np.float32(0.81)

    const float* __restrict__ xrow = (src ? wm : sig) + (size_t)row * T_LEN;
    const float4* __restrict__ xq  = (const float4*)xrow;   // per-lane quad stream

    float x1 = 0.f, x2 = 0.f, y1 = 0.f, y2 = 0.f, acc = 0.f;

    // w0 rotating prefetch buffers: pf{0,1,2}; at sub index u (global,
    // u = 3c+s) buffer u%3 holds sub u's data, and we issue loads for
    // sub u+2 into buffer (u+2)%3.  Distance-2 => ~2 sub-chunks of issue
    // time (~900 cyc) covers HBM latency.
    float4 pf0[NQ], pf1[NQ], pf2[NQ];
    if (wid == 0) {
        #pragma unroll
        for (int i = 0; i < NQ; ++i) pf0[i] = xq[i];        // sub u=0
        #pragma unroll
        for (int i = 0; i < NQ; ++i) pf1[i] = xq[NQ + i];   // sub u=1
    }

#define HP1(xx, oo)                                                          \
    {  float s1 = __fmaf_rn(hb0, xx, __fmul_rn(hb1, x1));                    \
       float s2 = __fmaf_rn(hb2, x2, s1); x2 = x1; x1 = xx;                  \
       float s3 = __fmaf_rn(hna1, y1, s2);                                   \
       oo = __fmaf_rn(hna2, y2, s3); y2 = y1; y1 = oo; }

#define LP1(xx, oo)                                                          \
    {  float s1 = __fmaf_rn(lb0, xx, __fmul_rn(lb1, x1));                    \
       float s2 = __fmaf_rn(lb2, x2, s1); x2 = x1; x1 = xx;                  \
       float s3 = __fmaf_rn(lna1, y1, s2);                                   \
       oo = __fmaf_rn(lna2, y2, s3); y2 = y1; y1 = oo; }

#define WSTEP(xx) \
    s1 = __fmaf_rn(-2.0f, x1, xx); \
    s2 = __fadd_rn(s1, x2); \
    s3 = __fmaf_rn(NA1, y1, s2); \
    yy = __fmaf_rn(NA2, y2, s3); \
    x2 = x1; x1 = xx; y2 = y1; y1 = yy; \
    acc = __fmaf_rn(yy, yy, acc);

// w0 sub-chunk: consume USE (sub u=3c+S), refill FILL with sub u+2
// (for S>=1 that reaches into chunk c+1; loads stay in flight across the
// lds-only barrier).  Max reach: c=831,S=2 -> quads 39952..39967 ->
// sample 159871 < 160000 (in-bounds).
#define W0SUB(USE, FILL, S)                                                  \
    {                                                                        \
        _Pragma("unroll")                                                    \
        for (int i = 0; i < NQ; ++i) {                                       \
            float4 v = USE[i];                                               \
            FILL[i] = xq[(3 * c + (S) + 2) * NQ + i];                        \
            float4 o;                                                        \
            HP1(v.x, o.x) HP1(v.y, o.y) HP1(v.z, o.z) HP1(v.w, o.w)          \
            ob[((S) * NQ + i) * 64 + lane] = o;                              \
        }                                                                    \
    }

// w1 sub-chunk: lp-transform register array V (holds sub S) in place into
// the same slot addresses.
#define W1SUB(V, S)                                                          \
    {                                                                        \
        _Pragma("unroll")                                                    \
        for (int i = 0; i < NQ; ++i) {                                       \
            float4 o;                                                        \
            LP1(V[i].x, o.x) LP1(V[i].y, o.y) LP1(V[i].z, o.z) LP1(V[i].w, o.w) \
            b[((S) * NQ + i) * 64 + lane] = o;                               \
        }                                                                    \
    }

// weight sub-chunk for parity EV on register array V (holds sub S):
// identical reset/end conditions and arithmetic to the verified kernel.
#define WGSUB(V, S)                                                          \
    {                                                                        \
        const int u = c * NSUB + (S);          /* global 64-sample index */  \
        const int m32 = u & 31;                                              \
        if ((m32 == (EV ? 0 : 16)) && (u >> 4) < NSEG) {                     \
            x1 = 0.f; x2 = 0.f; y1 = 0.f; y2 = 0.f; acc = 0.f;               \
        }                                                                    \
        _Pragma("unroll")                                                    \
        for (int i = 0; i < NQ; ++i) {                                       \
            float s1, s2, s3, yy;                                            \
            /* s1 = fma(-2,x1,x): product exact -> bit-identical to add form */ \
            WSTEP(V[i].x) WSTEP(V[i].y) WSTEP(V[i].z) WSTEP(V[i].w)          \
        }                                                                    \
        const int endm = EV ? 31 : 15;                                       \
        if (m32 == endm && u >= 31) {                                        \
            const int j = (u - 31) >> 4;                                     \
            float e = __fmul_rn(acc, 0.00048828125f);   /* /2048 exact */    \
            loud[((size_t)((band * 2 + src) * ROWS + row)) * NSEG + j] =     \
                __fmul_rn(10.0f, log10f(__fadd_rn(e, 1e-8f)));               \
        }                                                                    \
    }

#define LDSUB(V, S)                                                          \
    {                                                                        \
        _Pragma("unroll")                                                    \
        for (int i = 0; i < NQ; ++i) V[i] = b[((S) * NQ + i) * 64 + lane];   \
    }

    for (int iter = 0; iter < TOT_IT; ++iter) {
        if (wid == 0) {
            if (iter < NCHUNK) {
                const int c = iter;
                float4* __restrict__ ob = I[c % 3];
                // invariant: at chunk c, pf0 holds sub 3c, pf1 holds 3c+1
                W0SUB(pf0, pf2, 0)     // fill sub 3c+2
                W0SUB(pf1, pf0, 1)     // fill sub 3c+3 = next chunk sub 0
                W0SUB(pf2, pf1, 2)     // fill sub 3c+4 = next chunk sub 1
            }
        } else if (wid == 1) {
            const int c = iter - 1;
            if (c >= 0 && c < NCHUNK) {
                float4* __restrict__ b = I[c % 3];
                float4 vA[NQ], vB[NQ];
                LDSUB(vA, 0)                 // sub 0 reads
                LDSUB(vB, 1)                 // sub 1 reads (ahead)
                W1SUB(vA, 0)                 // compute+store sub 0
                LDSUB(vA, 2)                 // sub 2 reads (ahead)
                W1SUB(vB, 1)
                W1SUB(vA, 2)
            }
        } else {
            const bool EV = (wid == 2);        // wave-uniform
            const int c = iter - 2;
            if (c >= 0 && c < NCHUNK) {
                const float4* __restrict__ b = I[c % 3];
                float4 vA[NQ], vB[NQ];
                LDSUB(vA, 0)
                LDSUB(vB, 1)
                WGSUB(vA, 0)
                LDSUB(vA, 2)
                WGSUB(vB, 1)
                WGSUB(vA, 2)
            }
        }
        barrier_lds_only();
    }
#undef LDSUB
#undef WGSUB
#undef W1SUB
#undef W0SUB
#undef WSTEP
#undef LP1
#undef HP1
}

__global__ __launch_bounds__(256)
void tf_reduce_kernel(const float* __restrict__ loud, float* __restrict__ out) {
    __shared__ double sh[256];
    const int per_band = ROWS * NSEG;       // 4960
    const int npairs   = NBANDS * per_band; // 39680
    double s = 0.0;
    for (int idx = threadIdx.x; idx < npairs; idx += 256) {
        int band = idx / per_band;
        int rs   = idx - band * per_band;
        float a = loud[(size_t)(band * 2 + 0) * per_band + rs];
        float b = loud[(size_t)(band * 2 + 1) * per_band + rs];
        s += fabs((double)b - (double)a);
    }
    sh[threadIdx.x] = s;
    __syncthreads();
    for (int off = 128; off > 0; off >>= 1) {
        if (threadIdx.x < off) sh[threadIdx.x] += sh[threadIdx.x + off];
        __syncthreads();
    }
    if (threadIdx.x == 0) out[0] = (float)(sh[0] / (double)npairs);
}

// Host-side coefficients: f64 with the reference's exact expression order,
// then cast each to f32 (mirrors tuple(np.float32(v / a0) ...)).
static void mk_hp(double cutoff, float* o) {
    const double w0    = 2.0 * M_PI * cutoff / 16000.0;
    const double alpha = sin(w0) / (2.0 * 0.707);
    const double cw    = cos(w0);
    const double b0 = (1.0 + cw) / 2.0;
    const double b1 = -(1.0 + cw);
    const double b2 = (1.0 + cw) / 2.0;
    const double a0 = 1.0 + alpha;
    const double a1 = -2.0 * cw;
    const double a2 = 1.0 - alpha;
    o[0] = (float)(b0 / a0); o[1] = (float)(b1 / a0); o[2] = (float)(b2 / a0);
    o[3] = (float)(a1 / a0); o[4] = (float)(a2 / a0);
}

static void mk_lp(double cutoff, float* o) {
    const double w0    = 2.0 * M_PI * cutoff / 16000.0;
    const double alpha = sin(w0) / (2.0 * 0.707);
    const double cw    = cos(w0);
    const double b0 = (1.0 - cw) / 2.0;
    const double b1 = 1.0 - cw;
    const double b2 = (1.0 - cw) / 2.0;
    const double a0 = 1.0 + alpha;
    const double a1 = -2.0 * cw;
    const double a2 = 1.0 - alpha;
    o[0] = (float)(b0 / a0); o[1] = (float)(b1 / a0); o[2] = (float)(b2 / a0);
    o[3] = (float)(a1 / a0); o[4] = (float)(a2 / a0);
}

extern "C" void kernel_launch(void* const* d_in, const int* in_sizes, int n_in,
                              void* d_out, int out_size, void* d_ws, size_t ws_size,
                              hipStream_t stream) {
    const float* sig = (const float*)d_in[0];
    const float* wm  = (const float*)d_in[1];
    float* loud = (float*)d_ws;   // 79360 floats = 310 KiB

    AllCoefs C;
    for (int i = 0; i < NBANDS; ++i) {
        mk_hp(1000.0 * (double)i,       C.h[i]);   // low_cut  = i*1000 exactly
        mk_lp(1000.0 * (double)(i + 1), C.l[i]);   // high_cut = (i+1)*1000 exactly
    }

    tf_pipe4_kernel<<<dim3(NBANDS), 256, 0, stream>>>(sig, wm, loud, C);
    tf_reduce_kernel<<<1, 256, 0, stream>>>(loud, (float*)d_out);
}

// Round 6
// 2151.930 us; speedup vs baseline: 1.0745x; 1.0240x over previous
//
#include <hip/hip_runtime.h>
#include <cmath>

#ifndef M_PI
#define M_PI 3.14159265358979323846
#endif

#define T_LEN   160000
#define NSEG    155
#define ROWS    32
#define NBANDS  8

#define CHUNK   128                  // samples per barrier interval
#define NQC     32                   // float4 quads per chunk per chain
#define NCHUNK  1248                 // 128*1248 = 159744 = all samples any segment uses
#define TOT_IT  (NCHUNK + 5)         // 6-stage pipeline drain
#define LOUD_FLOATS (NBANDS * 2 * ROWS * NSEG)   // 79360

struct AllCoefs {
    float h[NBANDS][5];   // b0 b1 b2 a1 a2 (a0-normalized, f32-cast like np.float32)
    float l[NBANDS][5];
};

// Workgroup barrier without the vmcnt(0) drain (only LDS carries inter-wave
// data; w0's global prefetch stays in flight across the barrier).
__device__ __forceinline__ void barrier_lds_only() {
    asm volatile("s_waitcnt lgkmcnt(0)\n\ts_barrier" ::: "memory");
}

// ============================ Fused pipeline =============================
// R6: 6-wave FIR/REC-split pipeline, ALL interfaces in LDS (R1's split done
// right).  Empirical law from R0-R5: wall = 5.5 cyc x instr-count of the
// critical wave, no fixed barrier term.  So: cut the critical wave from
// 1090 instr (5 VALU/sample) to 448 (3 VALU/sample) by splitting each
// biquad across two waves.  One block per (band,src), 32 chains, 6 waves:
//   wid0 FIRhp : global x (ping-pong prefetch) -> fA[c%3]      3 VALU/smp
//   wid4 REChp : fA[(c)%3] in place                            2
//   wid1 FIRlp : fA -> fB[c%3]                                 3
//   wid5 REClp : fB in place                                   2
//   wid2 FIRwB : fB -> fC[c%2]  BASE weight FIR, no resets     2
//                (+ stores x[0],x[1] of reset chunks to PS)
//   wid3 RECw  : fC -> loud, 64-lane dual parity (broadcast),  3
//                patches f[0],f[1] at segment starts from PS
// Critical waves = the FIR stages: 2x16x(load + 12 VALU + store) = 448.
// Segment geometry: 1024-sample stride = 8 chunks, so every segment
// start/end is chunk-aligned: even segs reset at c%16==0, end c%16==15,
// odd at c%16==8 / c%16==7 (c>=15); j=(c-15)/8.
// Base-f patch (bit-exact): at a reset the reference computes
//   f0 = fadd(fma(-2,0,x0), 0) = x0,  f1 = fadd(fma(-2,x0,x1), 0)
// which RECw reproduces from the stored x0,x1 (sign-of-zero differences
// are squared away in acc).  FIR/REC value-split itself verified bit-exact
// in R4 (absmax 0.0).
__global__ __launch_bounds__(384, 1)
void tf_pipe6_kernel(const float* __restrict__ sig, const float* __restrict__ wm,
                     float* __restrict__ loud, AllCoefs C) {
    __shared__ float4 fA[3][NQC * 32];     // hp FIR out / hp y (48 KiB)
    __shared__ float4 fB[3][NQC * 32];     // lp FIR out / lp y (48 KiB)
    __shared__ float4 fC[2][NQC * 32];     // base weight-FIR out (32 KiB)
    __shared__ float  PS[2][2][32];        // reset-chunk x[0],x[1] per chain

    const int band = blockIdx.x;
    const int src  = blockIdx.y;              // 0 = signal, 1 = watermark
    const int tid  = threadIdx.x;
    const int wid  = tid >> 6;                // 0..5
    const int lane = tid & 63;
    const int ch   = lane & 31;               // chain = batch row

    const float hb0 = C.h[band][0], hb1 = C.h[band][1], hb2 = C.h[band][2];
    const float hna1 = -C.h[band][3], hna2 = -C.h[band][4];
    const float lb0 = C.l[band][0], lb1 = C.l[band][1], lb2 = C.l[band][2];
    const float lna1 = -C.l[band][3], lna2 = -C.l[band][4];
    const float NA1 =  1.79999995231628417969f; // -np.float32(-1.8)
    const float NA2 = -0.810000002384185791f;   // -np.float32(0.81)

    const float* __restrict__ xrow = (src ? wm : sig) + (size_t)ch * T_LEN;
    const float4* __restrict__ xq  = (const float4*)xrow;   // global quad array

    float x1 = 0.f, x2 = 0.f, y1 = 0.f, y2 = 0.f, acc = 0.f;

    float4 pfA_[16], pfB_[16];                // w0 sub-chunk ping-pong prefetch
    if (wid == 0 && lane < 32) {
        #pragma unroll
        for (int i = 0; i < 16; ++i) pfA_[i] = xq[i];   // chunk 0, sub 0
    }

// FIR halves (3 VALU) and REC halves (2 VALU) — identical arithmetic and
// order to the R4 kernel verified BIT-EXACT (absmax 0.0).
#define FH(xx, oo) { float s1_ = __fmaf_rn(hb0, xx, __fmul_rn(hb1, x1)); \
                     oo = __fmaf_rn(hb2, x2, s1_); x2 = x1; x1 = xx; }
#define RH(ff, oo) { float s3_ = __fmaf_rn(hna1, y1, ff); \
                     oo = __fmaf_rn(hna2, y2, s3_); y2 = y1; y1 = oo; }
#define FL(xx, oo) { float s1_ = __fmaf_rn(lb0, xx, __fmul_rn(lb1, x1)); \
                     oo = __fmaf_rn(lb2, x2, s1_); x2 = x1; x1 = xx; }
#define RL(ff, oo) { float s3_ = __fmaf_rn(lna1, y1, ff); \
                     oo = __fmaf_rn(lna2, y2, s3_); y2 = y1; y1 = oo; }
#define FW(xx, oo) { float s1_ = __fmaf_rn(-2.0f, x1, xx); \
                     oo = __fadd_rn(s1_, x2); x2 = x1; x1 = xx; }
#define RW(ff)     { float s3_ = __fmaf_rn(NA1, y1, ff); \
                     float yy_ = __fmaf_rn(NA2, y2, s3_); \
                     y2 = y1; y1 = yy_; acc = __fmaf_rn(yy_, yy_, acc); }

    for (int iter = 0; iter < TOT_IT; ++iter) {
        if (wid == 0) {
            // ---- FIRhp: global x -> fA[c%3] (3 VALU/sample) ----
            const int c = iter;
            if (c < NCHUNK && lane < 32) {
                float4* __restrict__ ob = fA[c % 3];
                // sub 0: consume pfA_, refill pfB_ with sub 1
                #pragma unroll
                for (int i = 0; i < 16; ++i) {
                    float4 v = pfA_[i];
                    pfB_[i] = xq[(2 * c + 1) * 16 + i];
                    float4 o;
                    FH(v.x, o.x) FH(v.y, o.y) FH(v.z, o.z) FH(v.w, o.w)
                    ob[i * 32 + ch] = o;
                }
                // sub 1: consume pfB_, refill pfA_ with next chunk's sub 0
                #pragma unroll
                for (int i = 0; i < 16; ++i) {
                    float4 v = pfB_[i];
                    pfA_[i] = xq[(2 * c + 2) * 16 + i];
                    float4 o;
                    FH(v.x, o.x) FH(v.y, o.y) FH(v.z, o.z) FH(v.w, o.w)
                    ob[(16 + i) * 32 + ch] = o;
                }
                // max prefetch: c=1247 -> quads 39936..39951 -> sample
                // 159807 < 160000 (in-bounds); loads ride across barrier
            }
        } else if (wid == 4) {
            // ---- REChp: fA[c%3] in place (2 VALU/sample) ----
            const int c = iter - 1;
            if (c >= 0 && c < NCHUNK && lane < 32) {
                float4* __restrict__ b = fA[c % 3];
                #pragma unroll
                for (int g = 0; g < 2; ++g) {
                    float4 v[16];
                    #pragma unroll
                    for (int i = 0; i < 16; ++i) v[i] = b[(g * 16 + i) * 32 + ch];
                    #pragma unroll
                    for (int i = 0; i < 16; ++i) {
                        float4 o;
                        RH(v[i].x, o.x) RH(v[i].y, o.y) RH(v[i].z, o.z) RH(v[i].w, o.w)
                        b[(g * 16 + i) * 32 + ch] = o;
                    }
                }
            }
        } else if (wid == 1) {
            // ---- FIRlp: fA[c%3] -> fB[c%3] (3 VALU/sample) ----
            const int c = iter - 2;
            if (c >= 0 && c < NCHUNK && lane < 32) {
                const float4* __restrict__ ib = fA[c % 3];
                float4* __restrict__ ob = fB[c % 3];
                #pragma unroll
                for (int g = 0; g < 2; ++g) {
                    float4 v[16];
                    #pragma unroll
                    for (int i = 0; i < 16; ++i) v[i] = ib[(g * 16 + i) * 32 + ch];
                    #pragma unroll
                    for (int i = 0; i < 16; ++i) {
                        float4 o;
                        FL(v[i].x, o.x) FL(v[i].y, o.y) FL(v[i].z, o.z) FL(v[i].w, o.w)
                        ob[(g * 16 + i) * 32 + ch] = o;
                    }
                }
            }
        } else if (wid == 5) {
            // ---- REClp: fB[c%3] in place (2 VALU/sample) ----
            const int c = iter - 3;
            if (c >= 0 && c < NCHUNK && lane < 32) {
                float4* __restrict__ b = fB[c % 3];
                #pragma unroll
                for (int g = 0; g < 2; ++g) {
                    float4 v[16];
                    #pragma unroll
                    for (int i = 0; i < 16; ++i) v[i] = b[(g * 16 + i) * 32 + ch];
                    #pragma unroll
                    for (int i = 0; i < 16; ++i) {
                        float4 o;
                        RL(v[i].x, o.x) RL(v[i].y, o.y) RL(v[i].z, o.z) RL(v[i].w, o.w)
                        b[(g * 16 + i) * 32 + ch] = o;
                    }
                }
            }
        } else if (wid == 2) {
            // ---- FIRwB: fB[c%3] -> fC[c%2], base weight FIR, no resets ----
            const int c = iter - 4;
            if (c >= 0 && c < NCHUNK && lane < 32) {
                const float4* __restrict__ ib = fB[c % 3];
                float4* __restrict__ ob = fC[c & 1];
                #pragma unroll
                for (int g = 0; g < 2; ++g) {
                    float4 v[16];
                    #pragma unroll
                    for (int i = 0; i < 16; ++i) v[i] = ib[(g * 16 + i) * 32 + ch];
                    if (g == 0 && (c & 7) == 0) {
                        // stash raw x[0],x[1] for RECw's reset patch
                        PS[c & 1][0][ch] = v[0].x;
                        PS[c & 1][1][ch] = v[0].y;
                    }
                    #pragma unroll
                    for (int i = 0; i < 16; ++i) {
                        float4 o;
                        FW(v[i].x, o.x) FW(v[i].y, o.y) FW(v[i].z, o.z) FW(v[i].w, o.w)
                        ob[(g * 16 + i) * 32 + ch] = o;
                    }
                }
            }
        } else {
            // ---- RECw: fC[c%2] -> loud, 64-lane dual parity ----
            const int c = iter - 5;
            if (c >= 0 && c < NCHUNK) {
                const bool EVh = (lane < 32);     // lanes 0-31 even segs
                const float4* __restrict__ ib = fC[c & 1];
                const float ps0 = PS[c & 1][0][ch];
                const float ps1 = PS[c & 1][1][ch];
                const bool rst = ((c & 15) == (EVh ? 0 : 8)) && ((c >> 3) < NSEG);
                if (rst) { y1 = 0.f; y2 = 0.f; acc = 0.f; }
                #pragma unroll
                for (int g = 0; g < 2; ++g) {
                    float4 v[16];
                    #pragma unroll
                    for (int i = 0; i < 16; ++i) v[i] = ib[(g * 16 + i) * 32 + ch];
                    if (g == 0 && rst) {
                        // exact reference reset path: f0=x0, f1=fma(-2,x0,x1)
                        v[0].x = ps0;
                        v[0].y = __fmaf_rn(-2.0f, ps0, ps1);
                    }
                    #pragma unroll
                    for (int i = 0; i < 16; ++i) {
                        RW(v[i].x) RW(v[i].y) RW(v[i].z) RW(v[i].w)
                    }
                }
                const bool endf = ((c & 15) == (EVh ? 15 : 7)) && (c >= 15);
                if (endf) {
                    const int j = (c - 15) >> 3;
                    float e = __fmul_rn(acc, 0.00048828125f);   // /2048 exact
                    loud[((size_t)((band * 2 + src) * ROWS + ch)) * NSEG + j] =
                        __fmul_rn(10.0f, log10f(__fadd_rn(e, 1e-8f)));
                }
            }
        }
        barrier_lds_only();
    }
#undef FH
#undef RH
#undef FL
#undef RL
#undef FW
#undef RW
}

__global__ __launch_bounds__(256)
void tf_reduce_kernel(const float* __restrict__ loud, float* __restrict__ out) {
    __shared__ double sh[256];
    const int per_band = ROWS * NSEG;       // 4960
    const int npairs   = NBANDS * per_band; // 39680
    double s = 0.0;
    for (int idx = threadIdx.x; idx < npairs; idx += 256) {
        int band = idx / per_band;
        int rs   = idx - band * per_band;
        float a = loud[(size_t)(band * 2 + 0) * per_band + rs];
        float b = loud[(size_t)(band * 2 + 1) * per_band + rs];
        s += fabs((double)b - (double)a);
    }
    sh[threadIdx.x] = s;
    __syncthreads();
    for (int off = 128; off > 0; off >>= 1) {
        if (threadIdx.x < off) sh[threadIdx.x] += sh[threadIdx.x + off];
        __syncthreads();
    }
    if (threadIdx.x == 0) out[0] = (float)(sh[0] / (double)npairs);
}

// Host-side coefficients: f64 with the reference's exact expression order,
// then cast each to f32 (mirrors tuple(np.float32(v / a0) ...)).
static void mk_hp(double cutoff, float* o) {
    const double w0    = 2.0 * M_PI * cutoff / 16000.0;
    const double alpha = sin(w0) / (2.0 * 0.707);
    const double cw    = cos(w0);
    const double b0 = (1.0 + cw) / 2.0;
    const double b1 = -(1.0 + cw);
    const double b2 = (1.0 + cw) / 2.0;
    const double a0 = 1.0 + alpha;
    const double a1 = -2.0 * cw;
    const double a2 = 1.0 - alpha;
    o[0] = (float)(b0 / a0); o[1] = (float)(b1 / a0); o[2] = (float)(b2 / a0);
    o[3] = (float)(a1 / a0); o[4] = (float)(a2 / a0);
}

static void mk_lp(double cutoff, float* o) {
    const double w0    = 2.0 * M_PI * cutoff / 16000.0;
    const double alpha = sin(w0) / (2.0 * 0.707);
    const double cw    = cos(w0);
    const double b0 = (1.0 - cw) / 2.0;
    const double b1 = 1.0 - cw;
    const double b2 = (1.0 - cw) / 2.0;
    const double a0 = 1.0 + alpha;
    const double a1 = -2.0 * cw;
    const double a2 = 1.0 - alpha;
    o[0] = (float)(b0 / a0); o[1] = (float)(b1 / a0); o[2] = (float)(b2 / a0);
    o[3] = (float)(a1 / a0); o[4] = (float)(a2 / a0);
}

extern "C" void kernel_launch(void* const* d_in, const int* in_sizes, int n_in,
                              void* d_out, int out_size, void* d_ws, size_t ws_size,
                              hipStream_t stream) {
    const float* sig = (const float*)d_in[0];
    const float* wm  = (const float*)d_in[1];
    float* loud = (float*)d_ws;   // 79360 floats = 310 KiB

    AllCoefs C;
    for (int i = 0; i < NBANDS; ++i) {
        mk_hp(1000.0 * (double)i,       C.h[i]);   // low_cut  = i*1000 exactly
        mk_lp(1000.0 * (double)(i + 1), C.l[i]);   // high_cut = (i+1)*1000 exactly
    }

    tf_pipe6_kernel<<<dim3(NBANDS, 2), 384, 0, stream>>>(sig, wm, loud, C);
    tf_reduce_kernel<<<1, 256, 0, stream>>>(loud, (float*)d_out);
}

// Round 7
// 2106.870 us; speedup vs baseline: 1.0975x; 1.0214x over previous
//
#include <hip/hip_runtime.h>
#include <cmath>

#ifndef M_PI
#define M_PI 3.14159265358979323846
#endif

#define T_LEN   160000
#define NSEG    155
#define ROWS    32
#define NBANDS  8

#define CHUNK   128                  // samples per barrier interval
#define NQC     32                   // float4 quads per chunk per chain
#define NCHUNK  1248                 // 128*1248 = 159744 = all samples any segment uses
#define TOT_IT  (NCHUNK + 5)         // 6-stage pipeline drain
#define LOUD_FLOATS (NBANDS * 2 * ROWS * NSEG)   // 79360
#define NPART   64                   // reduce partial blocks

struct AllCoefs {
    float h[NBANDS][5];   // b0 b1 b2 a1 a2 (a0-normalized, f32-cast like np.float32)
    float l[NBANDS][5];
};

// Workgroup barrier without the vmcnt(0) drain (only LDS carries inter-wave
// data; w0's global prefetch stays in flight across the barrier).
__device__ __forceinline__ void barrier_lds_only() {
    asm volatile("s_waitcnt lgkmcnt(0)\n\ts_barrier" ::: "memory");
}

// ============================ Fused pipeline =============================
// R6 structure, UNCHANGED (verified bit-exact, steady 2044-2048 us).
// Measured law across R0-R6: pace = 31 cyc/sample invariant to wave count,
// chunk size, ILP, prefetch = the recurrence's 2 dependent FMAs/sample at
// single-wave dependent-use latency ~15.5 cyc.  Floor: 159744 x 2 x 15.5
// / 2.4GHz = 2063 us; this kernel measures 2044-2048 -> AT the floor.
// Bit-exactness is mandatory (band-0 hp is marginally stable: double pole
// at z=1), which forbids reassociation/lookahead/scan reformulations.
__global__ __launch_bounds__(384, 1)
void tf_pipe6_kernel(const float* __restrict__ sig, const float* __restrict__ wm,
                     float* __restrict__ loud, AllCoefs C) {
    __shared__ float4 fA[3][NQC * 32];     // hp FIR out / hp y (48 KiB)
    __shared__ float4 fB[3][NQC * 32];     // lp FIR out / lp y (48 KiB)
    __shared__ float4 fC[2][NQC * 32];     // base weight-FIR out (32 KiB)
    __shared__ float  PS[2][2][32];        // reset-chunk x[0],x[1] per chain

    const int band = blockIdx.x;
    const int src  = blockIdx.y;              // 0 = signal, 1 = watermark
    const int tid  = threadIdx.x;
    const int wid  = tid >> 6;                // 0..5
    const int lane = tid & 63;
    const int ch   = lane & 31;               // chain = batch row

    const float hb0 = C.h[band][0], hb1 = C.h[band][1], hb2 = C.h[band][2];
    const float hna1 = -C.h[band][3], hna2 = -C.h[band][4];
    const float lb0 = C.l[band][0], lb1 = C.l[band][1], lb2 = C.l[band][2];
    const float lna1 = -C.l[band][3], lna2 = -C.l[band][4];
    const float NA1 =  1.79999995231628417969f; // -np.float32(-1.8)
    const float NA2 = -0.810000002384185791f;   // -np.float32(0.81)

    const float* __restrict__ xrow = (src ? wm : sig) + (size_t)ch * T_LEN;
    const float4* __restrict__ xq  = (const float4*)xrow;   // global quad array

    float x1 = 0.f, x2 = 0.f, y1 = 0.f, y2 = 0.f, acc = 0.f;

    float4 pfA_[16], pfB_[16];                // w0 sub-chunk ping-pong prefetch
    if (wid == 0 && lane < 32) {
        #pragma unroll
        for (int i = 0; i < 16; ++i) pfA_[i] = xq[i];   // chunk 0, sub 0
    }

// FIR halves (3 VALU) and REC halves (2 VALU) — identical arithmetic and
// order to the R4 kernel verified BIT-EXACT (absmax 0.0).
#define FH(xx, oo) { float s1_ = __fmaf_rn(hb0, xx, __fmul_rn(hb1, x1)); \
                     oo = __fmaf_rn(hb2, x2, s1_); x2 = x1; x1 = xx; }
#define RH(ff, oo) { float s3_ = __fmaf_rn(hna1, y1, ff); \
                     oo = __fmaf_rn(hna2, y2, s3_); y2 = y1; y1 = oo; }
#define FL(xx, oo) { float s1_ = __fmaf_rn(lb0, xx, __fmul_rn(lb1, x1)); \
                     oo = __fmaf_rn(lb2, x2, s1_); x2 = x1; x1 = xx; }
#define RL(ff, oo) { float s3_ = __fmaf_rn(lna1, y1, ff); \
                     oo = __fmaf_rn(lna2, y2, s3_); y2 = y1; y1 = oo; }
#define FW(xx, oo) { float s1_ = __fmaf_rn(-2.0f, x1, xx); \
                     oo = __fadd_rn(s1_, x2); x2 = x1; x1 = xx; }
#define RW(ff)     { float s3_ = __fmaf_rn(NA1, y1, ff); \
                     float yy_ = __fmaf_rn(NA2, y2, s3_); \
                     y2 = y1; y1 = yy_; acc = __fmaf_rn(yy_, yy_, acc); }

    for (int iter = 0; iter < TOT_IT; ++iter) {
        if (wid == 0) {
            // ---- FIRhp: global x -> fA[c%3] (3 VALU/sample) ----
            const int c = iter;
            if (c < NCHUNK && lane < 32) {
                float4* __restrict__ ob = fA[c % 3];
                // sub 0: consume pfA_, refill pfB_ with sub 1
                #pragma unroll
                for (int i = 0; i < 16; ++i) {
                    float4 v = pfA_[i];
                    pfB_[i] = xq[(2 * c + 1) * 16 + i];
                    float4 o;
                    FH(v.x, o.x) FH(v.y, o.y) FH(v.z, o.z) FH(v.w, o.w)
                    ob[i * 32 + ch] = o;
                }
                // sub 1: consume pfB_, refill pfA_ with next chunk's sub 0
                #pragma unroll
                for (int i = 0; i < 16; ++i) {
                    float4 v = pfB_[i];
                    pfA_[i] = xq[(2 * c + 2) * 16 + i];
                    float4 o;
                    FH(v.x, o.x) FH(v.y, o.y) FH(v.z, o.z) FH(v.w, o.w)
                    ob[(16 + i) * 32 + ch] = o;
                }
                // max prefetch: c=1247 -> quads 39936..39951 -> sample
                // 159807 < 160000 (in-bounds); loads ride across barrier
            }
        } else if (wid == 4) {
            // ---- REChp: fA[c%3] in place (2 VALU/sample) ----
            const int c = iter - 1;
            if (c >= 0 && c < NCHUNK && lane < 32) {
                float4* __restrict__ b = fA[c % 3];
                #pragma unroll
                for (int g = 0; g < 2; ++g) {
                    float4 v[16];
                    #pragma unroll
                    for (int i = 0; i < 16; ++i) v[i] = b[(g * 16 + i) * 32 + ch];
                    #pragma unroll
                    for (int i = 0; i < 16; ++i) {
                        float4 o;
                        RH(v[i].x, o.x) RH(v[i].y, o.y) RH(v[i].z, o.z) RH(v[i].w, o.w)
                        b[(g * 16 + i) * 32 + ch] = o;
                    }
                }
            }
        } else if (wid == 1) {
            // ---- FIRlp: fA[c%3] -> fB[c%3] (3 VALU/sample) ----
            const int c = iter - 2;
            if (c >= 0 && c < NCHUNK && lane < 32) {
                const float4* __restrict__ ib = fA[c % 3];
                float4* __restrict__ ob = fB[c % 3];
                #pragma unroll
                for (int g = 0; g < 2; ++g) {
                    float4 v[16];
                    #pragma unroll
                    for (int i = 0; i < 16; ++i) v[i] = ib[(g * 16 + i) * 32 + ch];
                    #pragma unroll
                    for (int i = 0; i < 16; ++i) {
                        float4 o;
                        FL(v[i].x, o.x) FL(v[i].y, o.y) FL(v[i].z, o.z) FL(v[i].w, o.w)
                        ob[(g * 16 + i) * 32 + ch] = o;
                    }
                }
            }
        } else if (wid == 5) {
            // ---- REClp: fB[c%3] in place (2 VALU/sample) ----
            const int c = iter - 3;
            if (c >= 0 && c < NCHUNK && lane < 32) {
                float4* __restrict__ b = fB[c % 3];
                #pragma unroll
                for (int g = 0; g < 2; ++g) {
                    float4 v[16];
                    #pragma unroll
                    for (int i = 0; i < 16; ++i) v[i] = b[(g * 16 + i) * 32 + ch];
                    #pragma unroll
                    for (int i = 0; i < 16; ++i) {
                        float4 o;
                        RL(v[i].x, o.x) RL(v[i].y, o.y) RL(v[i].z, o.z) RL(v[i].w, o.w)
                        b[(g * 16 + i) * 32 + ch] = o;
                    }
                }
            }
        } else if (wid == 2) {
            // ---- FIRwB: fB[c%3] -> fC[c%2], base weight FIR, no resets ----
            const int c = iter - 4;
            if (c >= 0 && c < NCHUNK && lane < 32) {
                const float4* __restrict__ ib = fB[c % 3];
                float4* __restrict__ ob = fC[c & 1];
                #pragma unroll
                for (int g = 0; g < 2; ++g) {
                    float4 v[16];
                    #pragma unroll
                    for (int i = 0; i < 16; ++i) v[i] = ib[(g * 16 + i) * 32 + ch];
                    if (g == 0 && (c & 7) == 0) {
                        // stash raw x[0],x[1] for RECw's reset patch
                        PS[c & 1][0][ch] = v[0].x;
                        PS[c & 1][1][ch] = v[0].y;
                    }
                    #pragma unroll
                    for (int i = 0; i < 16; ++i) {
                        float4 o;
                        FW(v[i].x, o.x) FW(v[i].y, o.y) FW(v[i].z, o.z) FW(v[i].w, o.w)
                        ob[(g * 16 + i) * 32 + ch] = o;
                    }
                }
            }
        } else {
            // ---- RECw: fC[c%2] -> loud, 64-lane dual parity ----
            const int c = iter - 5;
            if (c >= 0 && c < NCHUNK) {
                const bool EVh = (lane < 32);     // lanes 0-31 even segs
                const float4* __restrict__ ib = fC[c & 1];
                const float ps0 = PS[c & 1][0][ch];
                const float ps1 = PS[c & 1][1][ch];
                const bool rst = ((c & 15) == (EVh ? 0 : 8)) && ((c >> 3) < NSEG);
                if (rst) { y1 = 0.f; y2 = 0.f; acc = 0.f; }
                #pragma unroll
                for (int g = 0; g < 2; ++g) {
                    float4 v[16];
                    #pragma unroll
                    for (int i = 0; i < 16; ++i) v[i] = ib[(g * 16 + i) * 32 + ch];
                    if (g == 0 && rst) {
                        // exact reference reset path: f0=x0, f1=fma(-2,x0,x1)
                        v[0].x = ps0;
                        v[0].y = __fmaf_rn(-2.0f, ps0, ps1);
                    }
                    #pragma unroll
                    for (int i = 0; i < 16; ++i) {
                        RW(v[i].x) RW(v[i].y) RW(v[i].z) RW(v[i].w)
                    }
                }
                const bool endf = ((c & 15) == (EVh ? 15 : 7)) && (c >= 15);
                if (endf) {
                    const int j = (c - 15) >> 3;
                    float e = __fmul_rn(acc, 0.00048828125f);   // /2048 exact
                    loud[((size_t)((band * 2 + src) * ROWS + ch)) * NSEG + j] =
                        __fmul_rn(10.0f, log10f(__fadd_rn(e, 1e-8f)));
                }
            }
        }
        barrier_lds_only();
    }
#undef FH
#undef RH
#undef FL
#undef RL
#undef FW
#undef RW
}

// ======================================================================
// R7: parallelized reduction.  Double-accumulation in ANY partition order
// rounds to the same f32 as the previous single-block version (which
// matched JAX bit-for-bit, absmax 0.0), so splitting into 64 partials +
// a tree finalize is rounding-safe.
// ======================================================================
__global__ __launch_bounds__(256)
void tf_reduce_part(const float* __restrict__ loud, double* __restrict__ part) {
    __shared__ double sh[256];
    const int per_band = ROWS * NSEG;       // 4960
    const int npairs   = NBANDS * per_band; // 39680
    double s = 0.0;
    for (int idx = blockIdx.x * 256 + threadIdx.x; idx < npairs; idx += NPART * 256) {
        int band = idx / per_band;
        int rs   = idx - band * per_band;
        float a = loud[(size_t)(band * 2 + 0) * per_band + rs];
        float b = loud[(size_t)(band * 2 + 1) * per_band + rs];
        s += fabs((double)b - (double)a);
    }
    sh[threadIdx.x] = s;
    __syncthreads();
    for (int off = 128; off > 0; off >>= 1) {
        if (threadIdx.x < off) sh[threadIdx.x] += sh[threadIdx.x + off];
        __syncthreads();
    }
    if (threadIdx.x == 0) part[blockIdx.x] = sh[0];
}

__global__ __launch_bounds__(64)
void tf_reduce_fin(const double* __restrict__ part, float* __restrict__ out) {
    __shared__ double sh[64];
    sh[threadIdx.x] = part[threadIdx.x];
    __syncthreads();
    for (int off = 32; off > 0; off >>= 1) {
        if (threadIdx.x < off) sh[threadIdx.x] += sh[threadIdx.x + off];
        __syncthreads();
    }
    if (threadIdx.x == 0)
        out[0] = (float)(sh[0] / (double)(NBANDS * ROWS * NSEG));
}

// Host-side coefficients: f64 with the reference's exact expression order,
// then cast each to f32 (mirrors tuple(np.float32(v / a0) ...)).
static void mk_hp(double cutoff, float* o) {
    const double w0    = 2.0 * M_PI * cutoff / 16000.0;
    const double alpha = sin(w0) / (2.0 * 0.707);
    const double cw    = cos(w0);
    const double b0 = (1.0 + cw) / 2.0;
    const double b1 = -(1.0 + cw);
    const double b2 = (1.0 + cw) / 2.0;
    const double a0 = 1.0 + alpha;
    const double a1 = -2.0 * cw;
    const double a2 = 1.0 - alpha;
    o[0] = (float)(b0 / a0); o[1] = (float)(b1 / a0); o[2] = (float)(b2 / a0);
    o[3] = (float)(a1 / a0); o[4] = (float)(a2 / a0);
}

static void mk_lp(double cutoff, float* o) {
    const double w0    = 2.0 * M_PI * cutoff / 16000.0;
    const double alpha = sin(w0) / (2.0 * 0.707);
    const double cw    = cos(w0);
    const double b0 = (1.0 - cw) / 2.0;
    const double b1 = 1.0 - cw;
    const double b2 = (1.0 - cw) / 2.0;
    const double a0 = 1.0 + alpha;
    const double a1 = -2.0 * cw;
    const double a2 = 1.0 - alpha;
    o[0] = (float)(b0 / a0); o[1] = (float)(b1 / a0); o[2] = (float)(b2 / a0);
    o[3] = (float)(a1 / a0); o[4] = (float)(a2 / a0);
}

extern "C" void kernel_launch(void* const* d_in, const int* in_sizes, int n_in,
                              void* d_out, int out_size, void* d_ws, size_t ws_size,
                              hipStream_t stream) {
    const float* sig = (const float*)d_in[0];
    const float* wm  = (const float*)d_in[1];
    float*  loud = (float*)d_ws;                       // 79360 floats = 310 KiB
    double* part = (double*)((char*)d_ws + (size_t)LOUD_FLOATS * 4);  // 8B-aligned

    AllCoefs C;
    for (int i = 0; i < NBANDS; ++i) {
        mk_hp(1000.0 * (double)i,       C.h[i]);   // low_cut  = i*1000 exactly
        mk_lp(1000.0 * (double)(i + 1), C.l[i]);   // high_cut = (i+1)*1000 exactly
    }

    tf_pipe6_kernel<<<dim3(NBANDS, 2), 384, 0, stream>>>(sig, wm, loud, C);
    tf_reduce_part<<<NPART, 256, 0, stream>>>(loud, part);
    tf_reduce_fin<<<1, 64, 0, stream>>>(part, (float*)d_out);
}